// Round 8
// baseline (187.584 us; speedup 1.0000x reference)
//
#include <hip/hip_runtime.h>
#include <hip/hip_bf16.h>

#define SEQ 2048
#define DM  1024
#define NH  16
#define DK  64
#define MROWS 4096  // BATCH*SEQ

typedef __attribute__((ext_vector_type(8))) short short8;
typedef __attribute__((ext_vector_type(4))) short short4v;
typedef __attribute__((ext_vector_type(4))) float float4v;
typedef __attribute__((ext_vector_type(2))) unsigned uint2v;

typedef const __attribute__((address_space(1))) unsigned gu32;
typedef __attribute__((address_space(3))) unsigned lu32;

__device__ __forceinline__ void gl2lds16(const void* g, void* l) {
  __builtin_amdgcn_global_load_lds((gu32*)g, (lu32*)l, 16, 0, 0);
}

__device__ __forceinline__ short f2bf(float f) {  // RNE
  union { float f; unsigned u; } v; v.f = f;
  unsigned r = v.u + 0x7fffu + ((v.u >> 16) & 1u);
  return (short)(r >> 16);
}

#if __has_builtin(__builtin_amdgcn_exp2f)
#define EXP2(x) __builtin_amdgcn_exp2f(x)
#else
#define EXP2(x) exp2f(x)
#endif

__device__ __forceinline__ unsigned pack_bfu(float a, float b) {
  unsigned ua = __float_as_uint(a) + 0x8000u;
  unsigned ub = __float_as_uint(b) + 0x8000u;
#if __has_builtin(__builtin_amdgcn_perm)
  return __builtin_amdgcn_perm(ub, ua, 0x07060302u);
#else
  return (ua >> 16) | (ub & 0xffff0000u);
#endif
}

__global__ __launch_bounds__(256) void cvt_kernel(
    const float* __restrict__ in, short* __restrict__ out) {
  int i = blockIdx.x * 256 + threadIdx.x;
  float4v f = ((const float4v*)in)[i];
  short4v s;
#pragma unroll
  for (int j = 0; j < 4; ++j) s[j] = f2bf(f[j]);
  ((short4v*)out)[i] = s;
}

__global__ __launch_bounds__(256) void cvt4_kernel(
    const float* __restrict__ a, const float* __restrict__ b,
    const float* __restrict__ c, const float* __restrict__ d,
    short* __restrict__ out) {
  const float* srcs[4] = {a, b, c, d};
  const float* s = srcs[blockIdx.y];
  int i = blockIdx.x * 256 + threadIdx.x;
  float4v f = ((const float4v*)s)[i];
  short4v sv;
#pragma unroll
  for (int j = 0; j < 4; ++j) sv[j] = f2bf(f[j]);
  ((short4v*)(out + (size_t)blockIdx.y * DM * DM))[i] = sv;
}

// C[m,n] = sum_k A[m,k]*B[n,k]. Small tile TM x TN (TM=64), 4 waves in 2x2
// (each 32 x TN/2), BK=64, SINGLE-buffered 24/16 KB LDS -> 6/4 blocks per CU
// co-resident: latency hiding via TLP (m114), not intra-block pipelining.
// glls w16 staging with XOR source-swizzle -> conflict-free b128 frag reads.
// grid.x = n-blocks -> XCD = flat%8 owns a weight column (L2-resident).
template<int TM, int TN, int MINW, typename TC>
__global__ __launch_bounds__(256, MINW) void gemm_bt(
    const short* __restrict__ A, const short* __restrict__ Bw0,
    TC* __restrict__ C0, int M, int N, int K, size_t strB, size_t strC,
    short* __restrict__ vtOut, float qs0)
{
  constexpr int NI = TN / 32;           // 16-col tiles per wave
  constexpr int CA = TM * 64 / (8 * 256);
  constexpr int CB = TN * 64 / (8 * 256);
  constexpr int STG = (TM + TN) * 64;
  constexpr int TSZ = TN * 72;
  constexpr int SM_SZ = (TN == 128 && TSZ > STG) ? TSZ : STG;
  __shared__ __align__(16) short SMEM[SM_SZ];
  short* Al = SMEM;
  short* Bl = SMEM + TM * 64;

  const short* Bw = Bw0 + (size_t)blockIdx.z * strB;
  TC* C = C0 + (size_t)blockIdx.z * strC;

  const int tid  = threadIdx.x;
  const int lane = tid & 63, wave = tid >> 6;
  const int l16  = lane & 15, quad = lane >> 4;
  const int wm   = (wave >> 1) * 32, wn = (wave & 1) * (TN / 2);
  const int cm   = blockIdx.y * TM, cn = blockIdx.x * TN;

  float4v acc[2][NI];
#pragma unroll
  for (int i = 0; i < 2; ++i)
#pragma unroll
    for (int j = 0; j < NI; ++j)
#pragma unroll
      for (int r = 0; r < 4; ++r) acc[i][j][r] = 0.f;

  const short* ag = A  + (size_t)cm * K;
  const short* bg = Bw + (size_t)cn * K;

  auto stage = [&](int k0) {
#pragma unroll
    for (int i = 0; i < CA; ++i) {
      int c = i * 256 + tid;
      int row = c >> 3, cg = (c & 7) ^ (row & 7);
      gl2lds16(ag + (size_t)row * K + k0 + cg * 8, &Al[(i * 4 + wave) * 512]);
    }
#pragma unroll
    for (int i = 0; i < CB; ++i) {
      int c = i * 256 + tid;
      int row = c >> 3, cg = (c & 7) ^ (row & 7);
      gl2lds16(bg + (size_t)row * K + k0 + cg * 8, &Bl[(i * 4 + wave) * 512]);
    }
  };
  auto compute = [&]() {
#pragma unroll
    for (int ks = 0; ks < 2; ++ks) {
      const int sw = ((ks * 4 + quad) ^ (l16 & 7)) << 3;
      short8 af[2], bfr[NI];
#pragma unroll
      for (int mi = 0; mi < 2; ++mi)
        af[mi] = *(const short8*)&Al[(wm + mi*16 + l16) * 64 + sw];
#pragma unroll
      for (int ni = 0; ni < NI; ++ni)
        bfr[ni] = *(const short8*)&Bl[(wn + ni*16 + l16) * 64 + sw];
#pragma unroll
      for (int mi = 0; mi < 2; ++mi)
#pragma unroll
        for (int ni = 0; ni < NI; ++ni)
          acc[mi][ni] = __builtin_amdgcn_mfma_f32_16x16x32_bf16(
              af[mi], bfr[ni], acc[mi][ni], 0, 0, 0);
    }
  };

  for (int k0 = 0; k0 < K; k0 += 64) {
    stage(k0);
    __syncthreads();   // drains glls (vmcnt); TLP across 4-6 blocks hides it
    compute();
    __syncthreads();
  }

  const float scl = (blockIdx.z == 0) ? qs0 : 1.f;

  if constexpr (TN == 128) {
    if (vtOut != nullptr && blockIdx.z == 2) {
      // V^T epilogue: T[n_local][m_local], stride 72
      short* T = SMEM;  // 128*72 = 9216 <= SM_SZ
#pragma unroll
      for (int mi = 0; mi < 2; ++mi)
#pragma unroll
        for (int ni = 0; ni < NI; ++ni)
#pragma unroll
          for (int r = 0; r < 4; ++r)
            T[(wn + ni*16 + l16) * 72 + wm + mi*16 + quad*4 + r] =
                f2bf(acc[mi][ni][r]);
      __syncthreads();
      const int nrow = tid >> 1, mo = (tid & 1) * 32;
      const int b = cm >> 11;
      const int s0 = (cm & (SEQ - 1)) + mo;
      short* vt = vtOut + ((size_t)b * DM + cn + nrow) * SEQ + s0;
#pragma unroll
      for (int j = 0; j < 4; ++j)
        *(short8*)(vt + j * 8) = *(const short8*)&T[nrow * 72 + mo + j * 8];
      return;
    }
  }
#pragma unroll
  for (int mi = 0; mi < 2; ++mi)
#pragma unroll
    for (int ni = 0; ni < NI; ++ni)
#pragma unroll
      for (int r = 0; r < 4; ++r) {
        int m = cm + wm + mi*16 + quad*4 + r;
        int n = cn + wn + ni*16 + l16;
        float v = acc[mi][ni][r] * scl;
        if constexpr (sizeof(TC) == 2) C[(size_t)m * N + n] = f2bf(v);
        else                           C[(size_t)m * N + n] = v;
      }
}

// Flash attention, S^T orientation, Q pre-scaled by log2(e)/sqrt(dk).
// 512 thr = 8 waves x 16 Q-rows -> 2 blocks/CU x 8 waves = 4 waves/SIMD.
// K/V dbuf via glls (1 barrier/iter), XOR-swizzled stride-64 LDS.
// Grid (NH, S/128, B): XCD = h%8 -> K/V for 2 heads resident per XCD L2.
__global__ __launch_bounds__(512, 4) void flash_kernel(
    const short* __restrict__ Q, const short* __restrict__ Kg,
    const short* __restrict__ VTg, short* __restrict__ AO)
{
  __shared__ __align__(16) short Kl[2][64 * 64];
  __shared__ __align__(16) short Vt[2][64 * 64];
  __shared__ __align__(16) short Pl[8][16 * 64];
  __shared__ float lsumL[8][16];
  const int tid  = threadIdx.x;
  const int lane = tid & 63, wave = tid >> 6;   // 8 waves
  const int l16  = lane & 15, quad = lane >> 4;
  const int hc   = blockIdx.x * DK;
  const int q0   = blockIdx.y * 128;
  const size_t base = (size_t)blockIdx.z * SEQ;

  // Q as B-operand: B[k=d][n=qrow], 16 rows per wave
  short8 qfr[2];
#pragma unroll
  for (int ks = 0; ks < 2; ++ks)
    qfr[ks] = *(const short8*)(Q + (base + q0 + wave*16 + l16) * DM
                               + hc + ks*32 + quad*8);

  float4v O[4];
  float lsum = 0.f;
#pragma unroll
  for (int nt = 0; nt < 4; ++nt)
#pragma unroll
    for (int r = 0; r < 4; ++r) O[nt][r] = 0.f;

  const float4v z4 = {0.f, 0.f, 0.f, 0.f};
  const short* vtb = VTg + ((size_t)blockIdx.z * DM + hc) * SEQ;

  auto stageKV = [&](int buf, int kb) {   // 512 thr: 1 chunk each per matrix
    int row = tid >> 3, cg = (tid & 7) ^ (row & 7);
    gl2lds16(Kg + (base + kb*64 + row) * DM + hc + cg * 8, &Kl[buf][wave * 512]);
    gl2lds16(vtb + (size_t)row * SEQ + kb*64 + cg * 8, &Vt[buf][wave * 512]);
  };

  stageKV(0, 0);
  __syncthreads();

  int cur = 0;
  for (int kb = 0; kb < SEQ / 64; ++kb) {
    if (kb + 1 < SEQ / 64) stageKV(cur ^ 1, kb + 1);

    // S^T = K.Q^T : A = K-frag (m=key), B = Q-frag (n=qrow)
    float4v s[4];
#pragma unroll
    for (int kf = 0; kf < 4; ++kf) {
      const int rowb = (kf*16 + l16) * 64;
      short8 k0 = *(const short8*)&Kl[cur][rowb + ((quad       ^ (l16 & 7)) << 3)];
      short8 k1 = *(const short8*)&Kl[cur][rowb + (((4 + quad) ^ (l16 & 7)) << 3)];
      float4v t = __builtin_amdgcn_mfma_f32_16x16x32_bf16(k0, qfr[0], z4, 0, 0, 0);
      s[kf]     = __builtin_amdgcn_mfma_f32_16x16x32_bf16(k1, qfr[1], t, 0, 0, 0);
    }
#pragma unroll
    for (int kf = 0; kf < 4; ++kf) {
      float p0 = EXP2(s[kf][0]), p1 = EXP2(s[kf][1]);
      float p2 = EXP2(s[kf][2]), p3 = EXP2(s[kf][3]);
      lsum += (p0 + p1) + (p2 + p3);
      uint2v pk;
      pk[0] = pack_bfu(p0, p1);
      pk[1] = pack_bfu(p2, p3);
      *(uint2v*)&Pl[wave][l16 * 64 +
                          ((kf*16 + quad*4) ^ ((l16 & 7) << 3))] = pk;
    }
    // O += P.V (Pl row private to wave; per-wave DS pipe is in-order)
#pragma unroll
    for (int ks = 0; ks < 2; ++ks) {
      const int sw = ((ks*4 + quad) ^ (l16 & 7)) << 3;
      short8 pf = *(const short8*)&Pl[wave][l16 * 64 + sw];
#pragma unroll
      for (int nt = 0; nt < 4; ++nt) {
        short8 vf = *(const short8*)&Vt[cur][(nt*16 + l16) * 64 + sw];
        O[nt] = __builtin_amdgcn_mfma_f32_16x16x32_bf16(pf, vf, O[nt], 0, 0, 0);
      }
    }
    __syncthreads();
    cur ^= 1;
  }

  // row-sum: reduce over quads (lanes sharing l16), redistribute via LDS
  {
    float l = lsum;
    l += __shfl_xor(l, 16, 64);
    l += __shfl_xor(l, 32, 64);
    lsumL[wave][l16] = l;
  }
  float inv[4];
#pragma unroll
  for (int r = 0; r < 4; ++r) inv[r] = 1.f / lsumL[wave][quad*4 + r];
#pragma unroll
  for (int nt = 0; nt < 4; ++nt)
#pragma unroll
    for (int r = 0; r < 4; ++r) {
      int m = q0 + wave*16 + quad*4 + r;
      AO[(base + m) * DM + hc + nt*16 + l16] = f2bf(O[nt][r] * inv[r]);
    }
}

extern "C" void kernel_launch(void* const* d_in, const int* in_sizes, int n_in,
                              void* d_out, int out_size, void* d_ws, size_t ws_size,
                              hipStream_t stream) {
  (void)in_sizes; (void)n_in; (void)out_size; (void)ws_size;
  const float* x  = (const float*)d_in[0];
  const float* Wq = (const float*)d_in[1];
  const float* Wk = (const float*)d_in[2];
  const float* Wv = (const float*)d_in[3];
  const float* Wo = (const float*)d_in[4];
  float* out = (float*)d_out;

  const size_t NX = (size_t)MROWS * DM;
  const size_t NW = (size_t)DM * DM;
  short* xb  = (short*)d_ws;
  short* Wqb = xb  + NX;                  // Wq,Wk,Wv,Wo contiguous
  short* Qb  = Wqb + 4 * NW;
  short* Kb  = Qb  + NX;
  short* AO  = Kb  + NX;
  short* VTb = AO  + NX;                  // V^T: (B*DM, SEQ)

  cvt_kernel<<<dim3(NX / 4 / 256), 256, 0, stream>>>(x, xb);
  cvt4_kernel<<<dim3(NW / 4 / 256, 4), 256, 0, stream>>>(Wq, Wk, Wv, Wo, Wqb);

  const float qs = 0.18033688011112042f;  // log2(e)/sqrt(64), folded into Q

  // fused QKV: 64x128 tiles, grid 1536 = 6 blocks/CU all co-resident
  gemm_bt<64, 128, 6, short><<<dim3(DM / 128, MROWS / 64, 3), 256, 0, stream>>>(
      xb, Wqb, Qb, MROWS, DM, DM, NW, NX, VTb, qs);

  flash_kernel<<<dim3(NH, SEQ / 128, 2), 512, 0, stream>>>(Qb, Kb, VTb, AO);

  // final: 64x64 tiles, grid 1024 = 4 blocks/CU
  gemm_bt<64, 64, 6, float><<<dim3(DM / 64, MROWS / 64, 1), 256, 0, stream>>>(
      AO, Wqb + 3 * NW, out, MROWS, DM, DM, 0, 0, nullptr, 1.f);
}

// Round 9
// 181.462 us; speedup vs baseline: 1.0337x; 1.0337x over previous
//
#include <hip/hip_runtime.h>
#include <hip/hip_bf16.h>

#define SEQ 2048
#define DM  1024
#define NH  16
#define DK  64
#define MROWS 4096  // BATCH*SEQ

typedef __attribute__((ext_vector_type(8))) short short8;
typedef __attribute__((ext_vector_type(4))) short short4v;
typedef __attribute__((ext_vector_type(4))) float float4v;
typedef __attribute__((ext_vector_type(2))) unsigned uint2v;

typedef const __attribute__((address_space(1))) unsigned gu32;
typedef __attribute__((address_space(3))) unsigned lu32;

__device__ __forceinline__ void gl2lds16(const void* g, void* l) {
  __builtin_amdgcn_global_load_lds((gu32*)g, (lu32*)l, 16, 0, 0);
}

__device__ __forceinline__ short f2bf(float f) {  // RNE
  union { float f; unsigned u; } v; v.f = f;
  unsigned r = v.u + 0x7fffu + ((v.u >> 16) & 1u);
  return (short)(r >> 16);
}

#if __has_builtin(__builtin_amdgcn_exp2f)
#define EXP2(x) __builtin_amdgcn_exp2f(x)
#else
#define EXP2(x) exp2f(x)
#endif

__device__ __forceinline__ unsigned pack_bfu(float a, float b) {
  unsigned ua = __float_as_uint(a) + 0x8000u;
  unsigned ub = __float_as_uint(b) + 0x8000u;
#if __has_builtin(__builtin_amdgcn_perm)
  return __builtin_amdgcn_perm(ub, ua, 0x07060302u);
#else
  return (ua >> 16) | (ub & 0xffff0000u);
#endif
}

// one kernel converts x (4M elems) + 4 weights (1M each) to bf16.
// region select is block-uniform (boundaries are multiples of 256 float4s).
__global__ __launch_bounds__(256) void cvt5_kernel(
    const float* __restrict__ x,  const float* __restrict__ Wq,
    const float* __restrict__ Wk, const float* __restrict__ Wv,
    const float* __restrict__ Wo, short* __restrict__ xb,
    short* __restrict__ wb) {
  size_t c4 = (size_t)blockIdx.x * 256 + threadIdx.x;  // float4 index, 2M total
  const float* s; short* d; size_t off;
  if (c4 < (1u << 20)) { s = x; d = xb; off = c4; }
  else {
    size_t j = c4 - (1u << 20);
    int w = (int)(j >> 18);
    off = j & ((1u << 18) - 1);
    s = (w == 0) ? Wq : (w == 1) ? Wk : (w == 2) ? Wv : Wo;
    d = wb + ((size_t)w << 20);
  }
  float4v f = ((const float4v*)s)[off];
  short4v sv;
#pragma unroll
  for (int j = 0; j < 4; ++j) sv[j] = f2bf(f[j]);
  ((short4v*)d)[off] = sv;
}

// C[m,n] = sum_k A[m,k]*B[n,k]. Block tile (MI*16*RW) x (NI*16*CW),
// RW*CW waves, BK=64, glls w16 staging with XOR source-swizzle (conflict-free
// b128 frag reads, stride 64, no padding), single-buffered, 2 barriers/iter.
// Grid is m-fastest: XCD = m-slab%8 -> A is L2-resident per XCD.
// z picks weight/output (strB/strC); z==0 scales by qs0; z==2+vtOut -> V^T.
template<int MI, int NI, int RW, int CW, int MINW, typename TC>
__global__ __launch_bounds__(RW*CW*64, MINW) void gemm_bt(
    const short* __restrict__ A, const short* __restrict__ Bw0,
    TC* __restrict__ C0, int M, int N, int K, size_t strB, size_t strC,
    short* __restrict__ vtOut, float qs0)
{
  constexpr int NWAVES = RW * CW, THREADS = NWAVES * 64;
  constexpr int TM = MI * 16 * RW, TN = NI * 16 * CW;
  constexpr int CA = TM * 64 / (8 * THREADS);
  constexpr int CB = TN * 64 / (8 * THREADS);
  constexpr int STG = (TM + TN) * 64;
  constexpr int TSZ = (RW == 1 && TN == 128) ? 128 * 72 : 0;
  constexpr int SM_SZ = STG > TSZ ? STG : TSZ;
  __shared__ __align__(16) short SMEM[SM_SZ];
  short* Al = SMEM;
  short* Bl = SMEM + TM * 64;

  const short* Bw = Bw0 + (size_t)blockIdx.z * strB;
  TC* C = C0 + (size_t)blockIdx.z * strC;

  const int tid  = threadIdx.x;
  const int lane = tid & 63, wave = tid >> 6;
  const int l16  = lane & 15, quad = lane >> 4;
  const int wm   = (wave / CW) * MI * 16, wn = (wave % CW) * NI * 16;
  const int cm   = blockIdx.x * TM, cn = blockIdx.y * TN;  // m-fastest grid

  float4v acc[MI][NI];
#pragma unroll
  for (int i = 0; i < MI; ++i)
#pragma unroll
    for (int j = 0; j < NI; ++j)
#pragma unroll
      for (int r = 0; r < 4; ++r) acc[i][j][r] = 0.f;

  const short* ag = A  + (size_t)cm * K;
  const short* bg = Bw + (size_t)cn * K;

  auto stage = [&](int k0) {
#pragma unroll
    for (int i = 0; i < CA; ++i) {
      int c = i * THREADS + tid;
      int row = c >> 3, cg = (c & 7) ^ (row & 7);
      gl2lds16(ag + (size_t)row * K + k0 + cg * 8,
               &Al[(i * NWAVES + wave) * 512]);
    }
#pragma unroll
    for (int i = 0; i < CB; ++i) {
      int c = i * THREADS + tid;
      int row = c >> 3, cg = (c & 7) ^ (row & 7);
      gl2lds16(bg + (size_t)row * K + k0 + cg * 8,
               &Bl[(i * NWAVES + wave) * 512]);
    }
  };
  auto compute = [&]() {
#pragma unroll
    for (int ks = 0; ks < 2; ++ks) {
      const int sw = ((ks * 4 + quad) ^ (l16 & 7)) << 3;
      short8 af[MI], bfr[NI];
#pragma unroll
      for (int mi = 0; mi < MI; ++mi)
        af[mi] = *(const short8*)&Al[(wm + mi*16 + l16) * 64 + sw];
#pragma unroll
      for (int ni = 0; ni < NI; ++ni)
        bfr[ni] = *(const short8*)&Bl[(wn + ni*16 + l16) * 64 + sw];
#pragma unroll
      for (int mi = 0; mi < MI; ++mi)
#pragma unroll
        for (int ni = 0; ni < NI; ++ni)
          acc[mi][ni] = __builtin_amdgcn_mfma_f32_16x16x32_bf16(
              af[mi], bfr[ni], acc[mi][ni], 0, 0, 0);
    }
  };

  for (int k0 = 0; k0 < K; k0 += 64) {
    stage(k0);
    __syncthreads();   // drains glls (vmcnt)
    compute();
    __syncthreads();   // LDS safe to overwrite
  }

  const float scl = (blockIdx.z == 0) ? qs0 : 1.f;

  if constexpr (RW == 1 && TN == 128) {
    if (vtOut != nullptr && blockIdx.z == 2) {
      // V^T epilogue: T[n_local][m_local], stride 72 (m_local 0..63)
      short* T = SMEM;  // 128*72 = 9216 <= SM_SZ
#pragma unroll
      for (int mi = 0; mi < MI; ++mi)
#pragma unroll
        for (int ni = 0; ni < NI; ++ni)
#pragma unroll
          for (int r = 0; r < 4; ++r)
            T[(wn + ni*16 + l16) * 72 + mi*16 + quad*4 + r] =
                f2bf(acc[mi][ni][r]);
      __syncthreads();
      const int nrow = tid;            // 128 threads = 128 n-rows
      const int b = cm >> 11;
      const int s0 = cm & (SEQ - 1);
      short* vt = vtOut + ((size_t)b * DM + cn + nrow) * SEQ + s0;
#pragma unroll
      for (int j = 0; j < 8; ++j)
        *(short8*)(vt + j * 8) = *(const short8*)&T[nrow * 72 + j * 8];
      return;
    }
  }
#pragma unroll
  for (int mi = 0; mi < MI; ++mi)
#pragma unroll
    for (int ni = 0; ni < NI; ++ni)
#pragma unroll
      for (int r = 0; r < 4; ++r) {
        int m = cm + wm + mi*16 + quad*4 + r;
        int n = cn + wn + ni*16 + l16;
        float v = acc[mi][ni][r] * scl;
        if constexpr (sizeof(TC) == 2) C[(size_t)m * N + n] = f2bf(v);
        else                           C[(size_t)m * N + n] = v;
      }
}

// Flash attention, S^T orientation, Q pre-scaled by log2(e)/sqrt(dk).
// 512 thr = 8 waves x 16 Q-rows. K/V dbuf via glls (1 barrier/iter),
// XOR-swizzled stride-64 LDS. Grid (NH, S/128, B): XCD = h%8.
__global__ __launch_bounds__(512, 4) void flash_kernel(
    const short* __restrict__ Q, const short* __restrict__ Kg,
    const short* __restrict__ VTg, short* __restrict__ AO)
{
  __shared__ __align__(16) short Kl[2][64 * 64];
  __shared__ __align__(16) short Vt[2][64 * 64];
  __shared__ __align__(16) short Pl[8][16 * 64];
  __shared__ float lsumL[8][16];
  const int tid  = threadIdx.x;
  const int lane = tid & 63, wave = tid >> 6;   // 8 waves
  const int l16  = lane & 15, quad = lane >> 4;
  const int hc   = blockIdx.x * DK;
  const int q0   = blockIdx.y * 128;
  const size_t base = (size_t)blockIdx.z * SEQ;

  short8 qfr[2];
#pragma unroll
  for (int ks = 0; ks < 2; ++ks)
    qfr[ks] = *(const short8*)(Q + (base + q0 + wave*16 + l16) * DM
                               + hc + ks*32 + quad*8);

  float4v O[4];
  float lsum = 0.f;
#pragma unroll
  for (int nt = 0; nt < 4; ++nt)
#pragma unroll
    for (int r = 0; r < 4; ++r) O[nt][r] = 0.f;

  const float4v z4 = {0.f, 0.f, 0.f, 0.f};
  const short* vtb = VTg + ((size_t)blockIdx.z * DM + hc) * SEQ;

  auto stageKV = [&](int buf, int kb) {
    int row = tid >> 3, cg = (tid & 7) ^ (row & 7);
    gl2lds16(Kg + (base + kb*64 + row) * DM + hc + cg * 8, &Kl[buf][wave * 512]);
    gl2lds16(vtb + (size_t)row * SEQ + kb*64 + cg * 8, &Vt[buf][wave * 512]);
  };

  stageKV(0, 0);
  __syncthreads();

  int cur = 0;
  for (int kb = 0; kb < SEQ / 64; ++kb) {
    if (kb + 1 < SEQ / 64) stageKV(cur ^ 1, kb + 1);

    float4v s[4];
#pragma unroll
    for (int kf = 0; kf < 4; ++kf) {
      const int rowb = (kf*16 + l16) * 64;
      short8 k0 = *(const short8*)&Kl[cur][rowb + ((quad       ^ (l16 & 7)) << 3)];
      short8 k1 = *(const short8*)&Kl[cur][rowb + (((4 + quad) ^ (l16 & 7)) << 3)];
      float4v t = __builtin_amdgcn_mfma_f32_16x16x32_bf16(k0, qfr[0], z4, 0, 0, 0);
      s[kf]     = __builtin_amdgcn_mfma_f32_16x16x32_bf16(k1, qfr[1], t, 0, 0, 0);
    }
#pragma unroll
    for (int kf = 0; kf < 4; ++kf) {
      float p0 = EXP2(s[kf][0]), p1 = EXP2(s[kf][1]);
      float p2 = EXP2(s[kf][2]), p3 = EXP2(s[kf][3]);
      lsum += (p0 + p1) + (p2 + p3);
      uint2v pk;
      pk[0] = pack_bfu(p0, p1);
      pk[1] = pack_bfu(p2, p3);
      *(uint2v*)&Pl[wave][l16 * 64 +
                          ((kf*16 + quad*4) ^ ((l16 & 7) << 3))] = pk;
    }
#pragma unroll
    for (int ks = 0; ks < 2; ++ks) {
      const int sw = ((ks*4 + quad) ^ (l16 & 7)) << 3;
      short8 pf = *(const short8*)&Pl[wave][l16 * 64 + sw];
#pragma unroll
      for (int nt = 0; nt < 4; ++nt) {
        short8 vf = *(const short8*)&Vt[cur][(nt*16 + l16) * 64 + sw];
        O[nt] = __builtin_amdgcn_mfma_f32_16x16x32_bf16(pf, vf, O[nt], 0, 0, 0);
      }
    }
    __syncthreads();
    cur ^= 1;
  }

  {
    float l = lsum;
    l += __shfl_xor(l, 16, 64);
    l += __shfl_xor(l, 32, 64);
    lsumL[wave][l16] = l;
  }
  float inv[4];
#pragma unroll
  for (int r = 0; r < 4; ++r) inv[r] = 1.f / lsumL[wave][quad*4 + r];
#pragma unroll
  for (int nt = 0; nt < 4; ++nt)
#pragma unroll
    for (int r = 0; r < 4; ++r) {
      int m = q0 + wave*16 + quad*4 + r;
      AO[(base + m) * DM + hc + nt*16 + l16] = f2bf(O[nt][r] * inv[r]);
    }
}

extern "C" void kernel_launch(void* const* d_in, const int* in_sizes, int n_in,
                              void* d_out, int out_size, void* d_ws, size_t ws_size,
                              hipStream_t stream) {
  (void)in_sizes; (void)n_in; (void)out_size; (void)ws_size;
  const float* x  = (const float*)d_in[0];
  const float* Wq = (const float*)d_in[1];
  const float* Wk = (const float*)d_in[2];
  const float* Wv = (const float*)d_in[3];
  const float* Wo = (const float*)d_in[4];
  float* out = (float*)d_out;

  const size_t NX = (size_t)MROWS * DM;
  const size_t NW = (size_t)DM * DM;
  short* xb  = (short*)d_ws;
  short* Wqb = xb  + NX;                  // Wq,Wk,Wv,Wo contiguous
  short* Qb  = Wqb + 4 * NW;
  short* Kb  = Qb  + NX;
  short* AO  = Kb  + NX;
  short* VTb = AO  + NX;                  // V^T: (B*DM, SEQ)

  // fused conversion: x + all 4 weights, one dispatch (8M elems)
  cvt5_kernel<<<dim3(8192), 256, 0, stream>>>(x, Wq, Wk, Wv, Wo, xb, Wqb);

  const float qs = 0.18033688011112042f;  // log2(e)/sqrt(64), folded into Q

  // fused QKV: 64x128 tiles, 2 waves of 64x64, grid (m=64, n=8, z=3) = 1536
  // = 6 blocks/CU; XCD = m%8 -> A-slab L2-resident per XCD
  gemm_bt<4, 4, 1, 2, 3, short><<<dim3(MROWS / 64, DM / 128, 3), 128, 0, stream>>>(
      xb, Wqb, Qb, MROWS, DM, DM, NW, NX, VTb, qs);

  flash_kernel<<<dim3(NH, SEQ / 128, 2), 512, 0, stream>>>(Qb, Kb, VTb, AO);

  // final: 64x64 tiles, 2 waves of 32x64, grid (m=64, n=16) = 1024 = 4/CU
  gemm_bt<2, 4, 2, 1, 2, float><<<dim3(MROWS / 64, DM / 64, 1), 128, 0, stream>>>(
      AO, Wqb + 3 * NW, out, MROWS, DM, DM, 0, 0, nullptr, 1.f);
}